// Round 21
// baseline (503.989 us; speedup 1.0000x reference)
//
#include <hip/hip_runtime.h>
#include <stdint.h>

namespace {

constexpr int Tn = 512;
constexpr int Sn = 256;
constexpr float EPS = 1e-12f;

typedef _Float16 f16x8 __attribute__((ext_vector_type(8)));
typedef float    f32x4 __attribute__((ext_vector_type(4)));

// Barrier that drains ONLY lgkmcnt (LDS), never vmcnt (T4 pattern).
__device__ __forceinline__ void wg_barrier_lds() {
    asm volatile("s_waitcnt lgkmcnt(0)" ::: "memory");
    __builtin_amdgcn_s_barrier();
}

__launch_bounds__(256, 1)
__global__ void hmm_kernel(const float* __restrict__ emission,  // [B,T,S]
                           const float* __restrict__ weight,    // [S,S]
                           const float* __restrict__ init,      // [S]
                           float* __restrict__ out,             // [B,T,S]
                           int Bn)
{
    const int tid  = threadIdx.x;      // 0..255 == carried column
    const int wv   = tid >> 6;         // wave 0..3: owns cols 64wv .. 64wv+63
    const int lane = tid & 63;
    const int g    = lane >> 4;        // k-lane-group 0..3 (also my col-set)
    const int jj   = lane & 15;
    const int rA   = blockIdx.x * 2;               // first batch row
    const int rB   = (rA + 1 < Bn) ? rA + 1 : rA;  // second (clamped if odd B)

    __shared__ __align__(16) _Float16 wfA[2][Sn];  // dbuf w~ image, row A
    __shared__ __align__(16) _Float16 wfB[2][Sn];  // dbuf w~ image, row B
    __shared__ __align__(16) float    s_m[Sn];
    __shared__ __align__(16) float    s_z[Sn];

    // ---- prologue 1: transition softmax row stats (thread j owns row j) ----
    {
        const float* wr = weight + (size_t)tid * Sn;
        float m = -3.402823466e38f;
        #pragma unroll 4
        for (int i = 0; i < Sn; i += 4) {
            float4 v = *reinterpret_cast<const float4*>(wr + i);
            m = fmaxf(m, fmaxf(fmaxf(v.x, v.y), fmaxf(v.z, v.w)));
        }
        float z0 = 0.f, z1 = 0.f, z2 = 0.f, z3 = 0.f;
        #pragma unroll 4
        for (int i = 0; i < Sn; i += 4) {
            float4 v = *reinterpret_cast<const float4*>(wr + i);
            z0 += expf(v.x - m); z1 += expf(v.y - m);
            z2 += expf(v.z - m); z3 += expf(v.w - m);
        }
        s_m[tid] = m;
        s_z[tid] = 1.f / ((z0 + z1) + (z2 + z3));
        __syncthreads();
    }

    // ---- prologue 2: persistent B fragments, 4 col-sets per wave (f16) ----
    // Shared k-convention with A: chunk ck, group g, elem i <-> k = ck*32+g*8+i.
    // bf[s][ck] covers column 64*wv + 16*s + jj.  SHARED by both batch rows.
    f16x8 bf[4][8];
    #pragma unroll
    for (int s = 0; s < 4; ++s) {
        const int col = 64 * wv + 16 * s + jj;
        #pragma unroll
        for (int ck = 0; ck < 8; ++ck) {
            #pragma unroll
            for (int i = 0; i < 8; ++i) {
                const int k = ck * 32 + g * 8 + i;
                bf[s][ck][i] =
                    (_Float16)(expf(weight[(size_t)k * Sn + col] - s_m[k]) * s_z[k]);
            }
        }
    }
    // all-ones B operand: D = sum_k A[m,k] -> l1 in reg0 of EVERY lane
    const f16x8 ones8 = {(_Float16)1.f, (_Float16)1.f, (_Float16)1.f, (_Float16)1.f,
                         (_Float16)1.f, (_Float16)1.f, (_Float16)1.f, (_Float16)1.f};

    // ---- prologue 3: initial state softmax -> w~_0 images, e_1 ----
    const float* emA = emission + (size_t)rA * Tn * Sn + tid;
    const float* emB = emission + (size_t)rB * Tn * Sn + tid;
    float*       opA = out      + (size_t)rA * Tn * Sn + tid;
    float*       opB = out      + (size_t)rB * Tn * Sn + tid;
    {
        float i0 = init[lane], i1 = init[lane + 64],
              i2 = init[lane + 128], i3 = init[lane + 192];
        float mx = fmaxf(fmaxf(i0, i1), fmaxf(i2, i3));
        #pragma unroll
        for (int o = 32; o >= 1; o >>= 1) mx = fmaxf(mx, __shfl_xor(mx, o));
        float zz = expf(i0 - mx) + expf(i1 - mx) + expf(i2 - mx) + expf(i3 - mx);
        #pragma unroll
        for (int o = 32; o >= 1; o >>= 1) zz += __shfl_xor(zz, o);
        float u = expf(init[tid] - mx) / zz;
        wfA[0][tid] = (_Float16)(u * emA[0]);
        wfB[0][tid] = (_Float16)(u * emB[0]);
    }
    float enextA = emA[Sn];        // e_1[tid], row A
    float enextB = emB[Sn];        // e_1[tid], row B
    __syncthreads();

#define MFMA(A, B, D) __builtin_amdgcn_mfma_f32_16x16x32_f16((A), (B), (D), 0, 0, 0)

    #pragma unroll 1
    for (int t = 0; t < Tn; ++t) {
        const int p = t & 1;

        // (1) load ALL af fragments for BOTH rows — 16 ds_read_b128 in flight
        f16x8 afA[8], afB[8];
        #pragma unroll
        for (int ck = 0; ck < 8; ++ck) {
            afA[ck] = *reinterpret_cast<const f16x8*>(&wfA[p][ck * 32 + g * 8]);
            afB[ck] = *reinterpret_cast<const f16x8*>(&wfB[p][ck * 32 + g * 8]);
        }
        __builtin_amdgcn_sched_barrier(0);

        // (2) 10 interleaved MFMA chains — two independent rows fill each
        // other's dependency-chain latency
        f32x4 a0 = {0,0,0,0}, a1 = {0,0,0,0}, a2 = {0,0,0,0}, a3 = {0,0,0,0};
        f32x4 b0 = {0,0,0,0}, b1 = {0,0,0,0}, b2 = {0,0,0,0}, b3 = {0,0,0,0};
        f32x4 aS = {0,0,0,0}, bS = {0,0,0,0};
        #pragma unroll
        for (int ck = 0; ck < 8; ++ck) {
            a0 = MFMA(afA[ck], bf[0][ck], a0);  b0 = MFMA(afB[ck], bf[0][ck], b0);
            a1 = MFMA(afA[ck], bf[1][ck], a1);  b1 = MFMA(afB[ck], bf[1][ck], b1);
            a2 = MFMA(afA[ck], bf[2][ck], a2);  b2 = MFMA(afB[ck], bf[2][ck], b2);
            a3 = MFMA(afA[ck], bf[3][ck], a3);  b3 = MFMA(afB[ck], bf[3][ck], b3);
            aS = MFMA(afA[ck], ones8,    aS);   bS = MFMA(afB[ck], ones8,    bS);
        }

        // row-broadcast A => reg0 of chain s holds y[64wv+16s+jj]; my carried
        // column tid = 64wv+16g+jj  =>  pick chain s = g.
        float yA  = (g == 0) ? a0[0] : (g == 1) ? a1[0] : (g == 2) ? a2[0] : a3[0];
        float yB  = (g == 0) ? b0[0] : (g == 1) ? b1[0] : (g == 2) ? b2[0] : b3[0];
        float l1A = fmaxf(aS[0], EPS);
        float l1B = fmaxf(bS[0], EPS);

        // exact power-of-2 rescale from THIS step's l1
        float sigmaA = __uint_as_float(0x7f000000u -
                        (__float_as_uint(l1A) & 0x7f800000u));
        float sigmaB = __uint_as_float(0x7f000000u -
                        (__float_as_uint(l1B) & 0x7f800000u));

        // Bayes update + image writes (critical tail, both rows)
        float wnA = (yA * sigmaA) * enextA;
        float wnB = (yB * sigmaB) * enextB;
        wfA[p ^ 1][tid] = (_Float16)wnA;
        wfB[p ^ 1][tid] = (_Float16)wnB;

        // output stores — off the lgkm path, vmcnt untouched
        opA[(size_t)t * Sn] = yA * (1.f / l1A);
        opB[(size_t)t * Sn] = yB * (1.f / l1B);

        // prefetch e_{t+2} for both rows
        const int tp = (t + 2 < Tn) ? (t + 2) : (Tn - 1);
        enextA = emA[(size_t)tp * Sn];
        enextB = emB[(size_t)tp * Sn];

        wg_barrier_lds();     // single lgkm-only barrier per step
    }

#undef MFMA
}

} // namespace

extern "C" void kernel_launch(void* const* d_in, const int* in_sizes, int n_in,
                              void* d_out, int out_size, void* d_ws, size_t ws_size,
                              hipStream_t stream) {
    const float* emission = (const float*)d_in[0];
    const float* weight   = (const float*)d_in[1];
    const float* init     = (const float*)d_in[2];
    float* outp = (float*)d_out;
    const int Bn = in_sizes[0] / (Tn * Sn);   // 128 for the reference shapes
    const int nblk = (Bn + 1) / 2;            // 2 batch rows per block

    hipLaunchKernelGGL(hmm_kernel, dim3(nblk), dim3(256), 0, stream,
                       emission, weight, init, outp, Bn);
}